// Round 3
// baseline (1414.423 us; speedup 1.0000x reference)
//
#include <hip/hip_runtime.h>
#include <stdint.h>

// GenerativeWorldModel: B=2048,T=50,N=23,F=4,H=64,FUT=10. All I/O fp32.
// Pair-split: 2 waves per batch (wave s owns gate-col half jt=s).
// 1024 thr/block = 16 waves = 8 batches; 256 blocks; 16 waves/CU.
// GRU matmuls via mfma_f32_32x32x16_f16; GCN folded:
//   spatial = relu( (adj@x) @ Wg^T + rowsum(adj) * b_gcn )
// Register prefetch of next-step adj/x hides HBM latency.

typedef _Float16 f16;
typedef f16   f16x4  __attribute__((ext_vector_type(4)));
typedef f16   f16x8  __attribute__((ext_vector_type(8)));
typedef float f32x16 __attribute__((ext_vector_type(16)));
typedef float f32x4n __attribute__((ext_vector_type(4)));

// LDS map:
//  [0,55296): 54 B-fragments (fp16), 1024B each (frag*1024 + lane*16):
//    W_ih frag=nt*4+kt; W_hh +24; W_d1 48+kt; W_d2 52+kt (zero-pad n>=4)
//  55296 + pair*11968:
//    spat f16[32][68] (0, row stride 136B) | hbuf f16[32][68] (4352)
//    | adj f32[532] (8704) | x f32[96] (10832) | ax f32[23][8] (11216)
#define PAIR_STRIDE 11968
#define SMEM_BYTES (55296 + 8 * PAIR_STRIDE)

__device__ __forceinline__ f16x8 ldfrag(const char* base, int row, int off) {
    const char* p = base + row * 136 + off;     // 136B row stride: 2-way banks (free)
    const f16x4 lo = *(const f16x4*)p;          // ds_read_b64 (8B aligned)
    const f16x4 hi = *(const f16x4*)(p + 8);
    f16x8 r;
    r[0] = lo[0]; r[1] = lo[1]; r[2] = lo[2]; r[3] = lo[3];
    r[4] = hi[0]; r[5] = hi[1]; r[6] = hi[2]; r[7] = hi[3];
    return r;
}

__global__ __launch_bounds__(1024) void gwm_kernel(
    const float* __restrict__ xseq, const float* __restrict__ adjseq,
    const float* __restrict__ Wg,  const float* __restrict__ bg,
    const float* __restrict__ Wih, const float* __restrict__ Whh,
    const float* __restrict__ bih, const float* __restrict__ bhh,
    const float* __restrict__ Wd1, const float* __restrict__ bd1,
    const float* __restrict__ Wd2, const float* __restrict__ bd2,
    float* __restrict__ out)
{
    extern __shared__ char smem[];
    const int tid  = threadIdx.x;
    const int lane = tid & 63;
    const int wv   = tid >> 6;
    const int p    = wv >> 1;     // pair = batch slot
    const int s    = wv & 1;      // sub-wave: owns gate cols [32s, 32s+32)
    const int l31  = lane & 31;
    const int hf   = lane >> 5;

    // ---- pack fp32 weights into fp16 MFMA B-fragment order (once) ----
    for (int idx = tid; idx < 54 * 64; idx += 1024) {
        const int fi = idx >> 6;
        const int l  = idx & 63;
        const int ln = l & 31, lh = l >> 5;
        const float* src = nullptr;
        if (fi < 24) {                       // W_ih
            const int nt = fi >> 2, kt = fi & 3;
            src = Wih + (nt * 32 + ln) * 64 + kt * 16 + lh * 8;
        } else if (fi < 48) {                // W_hh
            const int f2 = fi - 24, nt = f2 >> 2, kt = f2 & 3;
            src = Whh + (nt * 32 + ln) * 64 + kt * 16 + lh * 8;
        } else if (fi < 52) {                // W_d1 (32x64)
            const int kt = fi - 48;
            src = Wd1 + ln * 64 + kt * 16 + lh * 8;
        } else {                             // W_d2 (4x32), n>=4 zero-padded
            const int kt = fi - 52;
            if (ln < 4) src = Wd2 + ln * 32 + kt * 16 + lh * 8;
        }
        f16x8 h;
        if (src) {
            const f32x4n v0 = *(const f32x4n*)src;
            const f32x4n v1 = *(const f32x4n*)(src + 4);
            #pragma unroll
            for (int j = 0; j < 4; ++j) { h[j] = (f16)v0[j]; h[4 + j] = (f16)v1[j]; }
        } else {
            #pragma unroll
            for (int j = 0; j < 8; ++j) h[j] = (f16)0.f;
        }
        *(f16x8*)(smem + fi * 1024 + l * 16) = h;
    }

    char*  pbase = smem + 55296 + p * PAIR_STRIDE;
    char*  spat  = pbase;                     // f16 [32][68]
    char*  hbuf  = pbase + 4352;              // f16 [32][68]
    float* adjL  = (float*)(pbase + 8704);    // f32 [532]
    float* xL    = (float*)(pbase + 10832);   // f32 [96]
    float* axL   = (float*)(pbase + 11216);   // f32 [23][8]

    // zero spat+hbuf (8704 B = 544 x 16B), split across the pair
    for (int i = s * 64 + lane; i < 544; i += 128)
        *(uint4*)(pbase + i * 16) = make_uint4(0u, 0u, 0u, 0u);

    // ---- per-lane fp32 constants ----
    float wg0[4], wg1[4];
    #pragma unroll
    for (int f = 0; f < 4; ++f) {
        wg0[f] = Wg[(2 * l31) * 4 + f];
        wg1[f] = Wg[(2 * l31 + 1) * 4 + f];
    }
    const float bg0 = bg[2 * l31], bg1 = bg[2 * l31 + 1];
    // gate tiles for this wave: nt = gate*2 + s
    const float bsR = bih[(0 * 2 + s) * 32 + l31] + bhh[(0 * 2 + s) * 32 + l31];
    const float bsZ = bih[(1 * 2 + s) * 32 + l31] + bhh[(1 * 2 + s) * 32 + l31];
    const float bIN = bih[(2 * 2 + s) * 32 + l31];
    const float bHN = bhh[(2 * 2 + s) * 32 + l31];
    const float bD1 = bd1[l31];
    const float bD2 = (l31 < 4) ? bd2[l31] : 0.0f;

    const int b = blockIdx.x * 8 + p;
    const float* xg = xseq   + (size_t)b * (50 * 92);
    const float* ag = adjseq + (size_t)b * (50 * 529);

    // ---- prefetch t=0 adj/x into registers ----
    f32x4n pfa, pfx;
    float  pft = 0.f;
    #pragma unroll
    for (int j = 0; j < 4; ++j) { pfa[j] = 0.f; pfx[j] = 0.f; }
    {
        const float* an = ag;
        if (s == 0) {
            #pragma unroll
            for (int j = 0; j < 4; ++j) pfa[j] = an[4 * lane + j];
            if (lane < 23) {
                #pragma unroll
                for (int j = 0; j < 4; ++j) pfx[j] = xg[4 * lane + j];
            }
        } else {
            #pragma unroll
            for (int j = 0; j < 4; ++j) pfa[j] = an[256 + 4 * lane + j];
            if (lane < 17) pft = an[512 + lane];
        }
    }

    f32x16 hc;   // own gate-col half of h, fp32 C-layout
    #pragma unroll
    for (int i = 0; i < 16; ++i) hc[i] = 0.f;

    for (int t = 0; t < 60; ++t) {
        // ---- phase A: consume prefetch -> LDS; issue prefetch t+1 ----
        if (t < 50) {
            if (s == 0) {
                *(f32x4n*)(adjL + 4 * lane) = pfa;
                if (lane < 23) *(f32x4n*)(xL + 4 * lane) = pfx;
            } else {
                *(f32x4n*)(adjL + 256 + 4 * lane) = pfa;
                if (lane < 17) adjL[512 + lane] = pft;
            }
            if (t + 1 < 50) {
                const float* an = ag + (t + 1) * 529;
                if (s == 0) {
                    #pragma unroll
                    for (int j = 0; j < 4; ++j) pfa[j] = an[4 * lane + j];
                    if (lane < 23) {
                        const float* xn = xg + (t + 1) * 92;
                        #pragma unroll
                        for (int j = 0; j < 4; ++j) pfx[j] = xn[4 * lane + j];
                    }
                } else {
                    #pragma unroll
                    for (int j = 0; j < 4; ++j) pfa[j] = an[256 + 4 * lane + j];
                    if (lane < 17) pft = an[512 + lane];
                }
            }
        }
        __syncthreads();   // staging visible (future: xL from decoder visible)

        // ---- phase BC: ax = adj@x + rowsum (own rows), then spatial (own rows) ----
        {
            const int  m_ax = (s == 0) ? lane : 12 + lane;
            const bool act  = (s == 0) ? (lane < 12) : (lane < 11);
            if (act) {
                float a0 = 0.f, a1 = 0.f, a2 = 0.f, a3 = 0.f, a4 = 0.f;
                for (int k = 0; k < 23; ++k) {
                    const float a = adjL[m_ax * 23 + k];
                    const f32x4n xv = *(const f32x4n*)(xL + 4 * k);  // broadcast
                    a0 += a * xv[0]; a1 += a * xv[1];
                    a2 += a * xv[2]; a3 += a * xv[3];
                    a4 += a;
                }
                f32x4n r4; r4[0] = a0; r4[1] = a1; r4[2] = a2; r4[3] = a3;
                *(f32x4n*)(axL + m_ax * 8) = r4;
                axL[m_ax * 8 + 4] = a4;
            }
            #pragma unroll
            for (int it = 0; it < 6; ++it) {
                const int m = (6 * s + it) * 2 + hf;
                if (m < 23) {
                    const f32x4n axv = *(const f32x4n*)(axL + m * 8);
                    const float  ar  = axL[m * 8 + 4];
                    float s0 = ar * bg0, s1 = ar * bg1;
                    #pragma unroll
                    for (int f = 0; f < 4; ++f) { s0 += axv[f] * wg0[f]; s1 += axv[f] * wg1[f]; }
                    s0 = fmaxf(s0, 0.f); s1 = fmaxf(s1, 0.f);
                    union { f16 h[2]; unsigned int u; } pk;
                    pk.h[0] = (f16)s0; pk.h[1] = (f16)s1;
                    *(unsigned int*)(spat + m * 136 + l31 * 4) = pk.u;
                }
            }
        }
        __syncthreads();   // spat complete (all 23 rows, both waves)

        // ---- phase D: GRU for own gate-col half via MFMA ----
        {
            f32x16 aR, aZ, aIN_, aHN_;
            #pragma unroll
            for (int i = 0; i < 16; ++i) {
                aR[i] = bsR; aZ[i] = bsZ; aIN_[i] = bIN; aHN_[i] = bHN;
            }
            #pragma unroll
            for (int kt = 0; kt < 4; ++kt) {
                const int off = kt * 32 + hf * 16;
                const f16x8 aSk = ldfrag(spat, l31, off);
                const f16x8 aHk = ldfrag(hbuf, l31, off);
                const f16x8 bIR = *(const f16x8*)(smem + ((0 * 2 + s) * 4 + kt) * 1024 + lane * 16);
                const f16x8 bHR = *(const f16x8*)(smem + (24 + (0 * 2 + s) * 4 + kt) * 1024 + lane * 16);
                const f16x8 bIZ = *(const f16x8*)(smem + ((1 * 2 + s) * 4 + kt) * 1024 + lane * 16);
                const f16x8 bHZ = *(const f16x8*)(smem + (24 + (1 * 2 + s) * 4 + kt) * 1024 + lane * 16);
                const f16x8 bIN8 = *(const f16x8*)(smem + ((2 * 2 + s) * 4 + kt) * 1024 + lane * 16);
                const f16x8 bHN8 = *(const f16x8*)(smem + (24 + (2 * 2 + s) * 4 + kt) * 1024 + lane * 16);
                aR   = __builtin_amdgcn_mfma_f32_32x32x16_f16(aSk, bIR,  aR,   0, 0, 0);
                aR   = __builtin_amdgcn_mfma_f32_32x32x16_f16(aHk, bHR,  aR,   0, 0, 0);
                aZ   = __builtin_amdgcn_mfma_f32_32x32x16_f16(aSk, bIZ,  aZ,   0, 0, 0);
                aZ   = __builtin_amdgcn_mfma_f32_32x32x16_f16(aHk, bHZ,  aZ,   0, 0, 0);
                aIN_ = __builtin_amdgcn_mfma_f32_32x32x16_f16(aSk, bIN8, aIN_, 0, 0, 0);
                aHN_ = __builtin_amdgcn_mfma_f32_32x32x16_f16(aHk, bHN8, aHN_, 0, 0, 0);
            }
            #pragma unroll
            for (int i = 0; i < 16; ++i) {
                const float r  = __builtin_amdgcn_rcpf(1.f + __expf(-aR[i]));
                const float z  = __builtin_amdgcn_rcpf(1.f + __expf(-aZ[i]));
                const float np = aIN_[i] + r * aHN_[i];
                const float th = 1.f - 2.f * __builtin_amdgcn_rcpf(1.f + __expf(2.f * np));
                const float hn = th + z * (hc[i] - th);
                hc[i] = hn;
                const int row = (i & 3) + 8 * (i >> 2) + 4 * hf;  // verified C/D row map
                *(f16*)(hbuf + row * 136 + (s * 32 + l31) * 2) = (f16)hn;
            }
        }
        __syncthreads();   // hbuf complete (for next-step aH and decoder)

        // ---- phase E (future, s==0 only): decode h -> prediction & next x ----
        if (t >= 50 && s == 0) {
            const int fs = t - 50;
            f32x16 d1a;
            #pragma unroll
            for (int i = 0; i < 16; ++i) d1a[i] = bD1;
            #pragma unroll
            for (int kt = 0; kt < 4; ++kt) {
                const f16x8 ah = ldfrag(hbuf, l31, kt * 32 + hf * 16);
                const f16x8 bw = *(const f16x8*)(smem + (48 + kt) * 1024 + lane * 16);
                d1a = __builtin_amdgcn_mfma_f32_32x32x16_f16(ah, bw, d1a, 0, 0, 0);
            }
            #pragma unroll
            for (int i = 0; i < 16; ++i) {     // relu(d1) -> A-layout in spat cols 0..31
                const int row = (i & 3) + 8 * (i >> 2) + 4 * hf;
                *(f16*)(spat + row * 136 + l31 * 2) = (f16)fmaxf(d1a[i], 0.f);
            }
            f32x16 d2a;
            #pragma unroll
            for (int i = 0; i < 16; ++i) d2a[i] = bD2;
            #pragma unroll
            for (int kt = 0; kt < 2; ++kt) {
                const f16x8 ad = ldfrag(spat, l31, kt * 32 + hf * 16);
                const f16x8 bw = *(const f16x8*)(smem + (52 + kt) * 1024 + lane * 16);
                d2a = __builtin_amdgcn_mfma_f32_32x32x16_f16(ad, bw, d2a, 0, 0, 0);
            }
            if (l31 < 4) {
                #pragma unroll
                for (int i = 0; i < 16; ++i) {
                    const int row = (i & 3) + 8 * (i >> 2) + 4 * hf;
                    if (row < 23) {
                        const float v = d2a[i];
                        out[(size_t)b * 920 + fs * 92 + row * 4 + l31] = v;
                        xL[row * 4 + l31] = v;   // feeds next step (visible after bar A)
                    }
                }
            }
        }
    }
}

extern "C" void kernel_launch(void* const* d_in, const int* in_sizes, int n_in,
                              void* d_out, int out_size, void* d_ws, size_t ws_size,
                              hipStream_t stream) {
    (void)in_sizes; (void)n_in; (void)d_ws; (void)ws_size; (void)out_size;
    hipFuncSetAttribute((const void*)gwm_kernel,
                        hipFuncAttributeMaxDynamicSharedMemorySize, SMEM_BYTES);
    gwm_kernel<<<dim3(256), dim3(1024), SMEM_BYTES, stream>>>(
        (const float*)d_in[0], (const float*)d_in[1], (const float*)d_in[2],
        (const float*)d_in[3], (const float*)d_in[4], (const float*)d_in[5],
        (const float*)d_in[6], (const float*)d_in[7], (const float*)d_in[8],
        (const float*)d_in[9], (const float*)d_in[10], (const float*)d_in[11],
        (float*)d_out);
}

// Round 4
// 570.853 us; speedup vs baseline: 2.4777x; 2.4777x over previous
//
#include <hip/hip_runtime.h>
#include <stdint.h>

// GenerativeWorldModel: B=2048,T=50,N=23,F=4,H=64,FUT=10. All I/O fp32.
// 1 wave = 1 batch, 512 thr/block (8 waves), 256 blocks, no barriers in loop.
// All GEMMs transposed (D[row=feature][col=node]) so C-layout lane = node =
// B-operand lane: h recurrence lives entirely in registers; B-frags rebuilt
// via shfl_xor(32). Biases folded as extra K-tile (bias col x ones frag).
//   E^T = [x|1]^T @ adj^T            (2 MFMA; rowsum via ones row)
//   S^T = relu(Wg_ext @ E^T)         (2 MFMA)
//   g^T = Wih_ext @ S_ext^T + Whh_ext @ h_ext^T   (56 MFMA)
//   dec: d1^T = relu(Wd1_ext@h^T); d2^T = Wd2_ext@d1^T (8 MFMA, future only)

typedef _Float16 f16;
typedef f16   f16x2  __attribute__((ext_vector_type(2)));
typedef f16   f16x8  __attribute__((ext_vector_type(8)));
typedef float f32x4n __attribute__((ext_vector_type(4)));
typedef float f32x16 __attribute__((ext_vector_type(16)));

#define WBYTES 69632            // 68 weight frags * 1024 B
#define PW 4736                 // per-wave: xL f32[128] (512B) + adjF f32[32*33] (4224B)
#define SMEM_BYTES (WBYTES + 8 * PW)   // 107520

static __device__ __forceinline__ unsigned pk2(float a, float b) {
    f16x2 h; h[0] = (f16)a; h[1] = (f16)b;
    return __builtin_bit_cast(unsigned, h);
}
static __device__ __forceinline__ f16x8 mkfrag(unsigned a, unsigned b, unsigned c, unsigned d) {
    uint4 u = make_uint4(a, b, c, d);
    return __builtin_bit_cast(f16x8, u);
}
static __device__ __forceinline__ unsigned shx32(unsigned v) {
    return (unsigned)__shfl_xor((int)v, 32, 64);
}
static __device__ __forceinline__ float sigm(float x) {
    return __builtin_amdgcn_rcpf(1.f + __expf(-x));
}
static __device__ __forceinline__ float tanhp(float x) {
    return 1.f - 2.f * __builtin_amdgcn_rcpf(1.f + __expf(2.f * x));
}
// C-layout f32x16 tile -> two B-frags (k-blocks [0,16) and [16,32) of tile)
static __device__ __forceinline__ void cvt_tile(const f32x16& v, int hf, f16x8& fe, f16x8& fo) {
    unsigned u0 = pk2(v[0], v[1]),  u1 = pk2(v[2], v[3]);
    unsigned u2 = pk2(v[4], v[5]),  u3 = pk2(v[6], v[7]);
    unsigned u4 = pk2(v[8], v[9]),  u5 = pk2(v[10], v[11]);
    unsigned u6 = pk2(v[12], v[13]), u7 = pk2(v[14], v[15]);
    unsigned sA = shx32(hf ? u0 : u2), sB = shx32(hf ? u1 : u3);
    unsigned sC = shx32(hf ? u4 : u6), sD = shx32(hf ? u5 : u7);
    fe = mkfrag(hf ? sA : u0, hf ? sB : u1, hf ? u2 : sA, hf ? u3 : sB);
    fo = mkfrag(hf ? sC : u4, hf ? sD : u5, hf ? u6 : sC, hf ? u7 : sD);
}

__global__ __launch_bounds__(512, 2) void gwm_kernel(
    const float* __restrict__ xseq, const float* __restrict__ adjseq,
    const float* __restrict__ Wg,  const float* __restrict__ bg,
    const float* __restrict__ Wih, const float* __restrict__ Whh,
    const float* __restrict__ bih, const float* __restrict__ bhh,
    const float* __restrict__ Wd1, const float* __restrict__ bd1,
    const float* __restrict__ Wd2, const float* __restrict__ bd2,
    float* __restrict__ out)
{
    extern __shared__ char smem[];
    const int tid  = threadIdx.x;
    const int lane = tid & 63;
    const int wv   = tid >> 6;
    const int l31  = lane & 31;
    const int hf   = lane >> 5;

    // ---- pack weights (A-frags, fp16) + bias columns into LDS (once) ----
    // fi 0..59: (side*6+tau)*5+kt for W_ih/W_hh tiles (kt4 = bias col)
    // fi 60..64: Wd1 (kt4 = bd1); fi 65..67: Wd2 kt0,kt1, bias
    for (int idx = tid; idx < 68 * 64; idx += 512) {
        const int fi = idx >> 6, l = idx & 63, ln = l & 31, lh = l >> 5;
        float v[8];
        #pragma unroll
        for (int j = 0; j < 8; ++j) v[j] = 0.f;
        if (fi < 60) {
            const int grp = fi / 5, kt = fi - grp * 5;
            const int side = grp / 6, tau = grp - side * 6;
            const float* W = side ? Whh : Wih;
            const int row = tau * 32 + ln;
            if (kt < 4) {
                const float* s = W + row * 64 + kt * 16 + lh * 8;
                #pragma unroll
                for (int j = 0; j < 8; ++j) v[j] = s[j];
            } else if (lh == 0) {
                if (side == 0) v[0] = bih[row] + (tau < 4 ? bhh[row] : 0.f);
                else           v[0] = (tau < 4) ? 0.f : bhh[row];
            }
        } else if (fi < 65) {
            const int kt = fi - 60;
            if (kt < 4) {
                const float* s = Wd1 + ln * 64 + kt * 16 + lh * 8;
                #pragma unroll
                for (int j = 0; j < 8; ++j) v[j] = s[j];
            } else if (lh == 0) v[0] = bd1[ln];
        } else {
            const int kt = fi - 65;
            if (kt < 2) {
                if (ln < 4) {
                    const float* s = Wd2 + ln * 32 + kt * 16 + lh * 8;
                    #pragma unroll
                    for (int j = 0; j < 8; ++j) v[j] = s[j];
                }
            } else if (lh == 0 && ln < 4) v[0] = bd2[ln];
        }
        f16x8 h8;
        #pragma unroll
        for (int j = 0; j < 8; ++j) h8[j] = (f16)v[j];
        *(f16x8*)(smem + fi * 1024 + l * 16) = h8;
    }

    char*  wbase = smem + WBYTES + wv * PW;
    float* xL    = (float*)wbase;          // f32[128] (92 real + zero pad)
    float* adjF  = (float*)(wbase + 512);  // f32[32*33] row-major adj, stride 33

    // zero-init wave-private LDS (pads must be 0, not NaN garbage)
    {
        f32x4n z4; z4[0] = z4[1] = z4[2] = z4[3] = 0.f;
        #pragma unroll
        for (int q = 0; q < 4; ++q) *(f32x4n*)(adjF + lane * 16 + q * 4) = z4;
        adjF[1024 + lane] = 0.f;                    // 1024..1055 tail
        if (lane < 32) adjF[1024 + 64 + lane] = 0.f; // up to 1056 (pad region)
        if (lane < 64) { if (lane + 64 < 128) xL[lane + 64] = 0.f; xL[lane] = 0.f; }
    }
    __syncthreads();   // weight frags visible

    // ---- per-lane constants ----
    // ones fragment (k'=0 -> 1) used for every bias K-tile
    const f16x8 bC = (hf == 0) ? mkfrag(pk2(1.f, 0.f), 0u, 0u, 0u)
                               : mkfrag(0u, 0u, 0u, 0u);
    // Wg_ext A-frags: A[c][f] = Wg[c][f] (f<4), bg[c] (f=4)
    f16x8 aWg0, aWg1;
    {
        const int c0 = l31, c1 = 32 + l31;
        aWg0 = hf ? mkfrag(0u,0u,0u,0u)
                  : mkfrag(pk2(Wg[c0*4], Wg[c0*4+1]), pk2(Wg[c0*4+2], Wg[c0*4+3]),
                           pk2(bg[c0], 0.f), 0u);
        aWg1 = hf ? mkfrag(0u,0u,0u,0u)
                  : mkfrag(pk2(Wg[c1*4], Wg[c1*4+1]), pk2(Wg[c1*4+2], Wg[c1*4+3]),
                           pk2(bg[c1], 0.f), 0u);
    }

    const int b = blockIdx.x * 8 + wv;
    const float* xg = xseq   + (size_t)b * (50 * 92);
    const float* ag = adjseq + (size_t)b * (50 * 529);
    float* outb = out + (size_t)b * 920;

    // ---- prefetch t=0 ----
    float pf[9]; f32x4n pfx;
    #pragma unroll
    for (int r = 0; r < 9; ++r) pf[r] = 0.f;
    pfx[0] = pfx[1] = pfx[2] = pfx[3] = 0.f;
    #pragma unroll
    for (int r = 0; r < 9; ++r) if (r < 8 || lane < 17) pf[r] = ag[lane + 64 * r];
    if (lane < 23) pfx = *(const f32x4n*)(xg + 4 * lane);

    // ---- recurrent state in registers ----
    f32x16 hC0, hC1;           // h fp32, C-layout (j 0..31 / 32..63)
    f16x8  bH[4];              // h fp16 B-frags (k-blocks of 16)
    #pragma unroll
    for (int i = 0; i < 16; ++i) { hC0[i] = 0.f; hC1[i] = 0.f; }
    #pragma unroll
    for (int kt = 0; kt < 4; ++kt) bH[kt] = mkfrag(0u, 0u, 0u, 0u);

    f32x16 z16;
    #pragma unroll
    for (int i = 0; i < 16; ++i) z16[i] = 0.f;

    auto mm = [&](f32x16 acc, int fi, f16x8 bfr) -> f32x16 {
        const f16x8 aW = *(const f16x8*)(smem + fi * 1024 + lane * 16);
        return __builtin_amdgcn_mfma_f32_32x32x16_f16(aW, bfr, acc, 0, 0, 0);
    };

    for (int t = 0; t < 60; ++t) {
        // ---- stage adj/x (history only); prefetch t+1 ----
        if (t < 50) {
            #pragma unroll
            for (int r = 0; r < 9; ++r) {
                if (r < 8 || lane < 17) {
                    const unsigned e = (unsigned)(lane + 64 * r);
                    const unsigned row = __umulhi(e, 186737709u);
                    const unsigned col = e - row * 23u;
                    adjF[row * 33 + col] = pf[r];
                }
            }
            if (lane < 23) *(f32x4n*)(xL + 4 * lane) = pfx;
            if (t + 1 < 50) {
                const float* a2 = ag + (t + 1) * 529;
                #pragma unroll
                for (int r = 0; r < 9; ++r) if (r < 8 || lane < 17) pf[r] = a2[lane + 64 * r];
                if (lane < 23) pfx = *(const f32x4n*)(xg + (t + 1) * 92 + 4 * lane);
            }
        }

        // ---- X^ A-frags: A[f][node] = x[node][f], f=4 -> ones ----
        f16x8 aX0, aX1;
        {
            float v0[8], v1[8];
            #pragma unroll
            for (int j = 0; j < 8; ++j) {
                const int n0 = 8 * hf + j, n1 = 16 + 8 * hf + j;
                const float x0 = xL[n0 * 4 + (l31 & 3)];
                const float x1 = xL[n1 * 4 + (l31 & 3)];
                v0[j] = (l31 < 4) ? x0 : ((l31 == 4) ? 1.f : 0.f);
                v1[j] = (l31 < 4) ? x1 : ((l31 == 4) ? 1.f : 0.f);
            }
            aX0 = mkfrag(pk2(v0[0],v0[1]), pk2(v0[2],v0[3]), pk2(v0[4],v0[5]), pk2(v0[6],v0[7]));
            aX1 = mkfrag(pk2(v1[0],v1[1]), pk2(v1[2],v1[3]), pk2(v1[4],v1[5]), pk2(v1[6],v1[7]));
        }
        // ---- adj^T B-frags: B[k][n=l31] = adj[n][k], stride-33 conflict-free ----
        f16x8 bA0, bA1;
        {
            float a0[8], a1[8];
            #pragma unroll
            for (int j = 0; j < 8; ++j) {
                a0[j] = adjF[l31 * 33 + 8 * hf + j];
                a1[j] = adjF[l31 * 33 + 16 + 8 * hf + j];
            }
            bA0 = mkfrag(pk2(a0[0],a0[1]), pk2(a0[2],a0[3]), pk2(a0[4],a0[5]), pk2(a0[6],a0[7]));
            bA1 = mkfrag(pk2(a1[0],a1[1]), pk2(a1[2],a1[3]), pk2(a1[4],a1[5]), pk2(a1[6],a1[7]));
        }
        // ---- E^T = X^T @ adj^T ----
        f32x16 accE = z16;
        accE = __builtin_amdgcn_mfma_f32_32x32x16_f16(aX0, bA0, accE, 0, 0, 0);
        accE = __builtin_amdgcn_mfma_f32_32x32x16_f16(aX1, bA1, accE, 0, 0, 0);
        // ---- bE frag (rows f0..4 real, rest zero) ----
        const unsigned p01 = pk2(accE[0], accE[1]), p23 = pk2(accE[2], accE[3]);
        const unsigned p4  = shx32(hf ? pk2(accE[0], 0.f) : 0u);
        const f16x8 bE = hf ? mkfrag(0u, 0u, 0u, 0u) : mkfrag(p01, p23, p4, 0u);
        // ---- spatial^T = relu(Wg_ext @ E^T) ----
        f32x16 s0 = z16, s1 = z16;
        s0 = __builtin_amdgcn_mfma_f32_32x32x16_f16(aWg0, bE, s0, 0, 0, 0);
        s1 = __builtin_amdgcn_mfma_f32_32x32x16_f16(aWg1, bE, s1, 0, 0, 0);
        #pragma unroll
        for (int i = 0; i < 16; ++i) { s0[i] = fmaxf(s0[i], 0.f); s1[i] = fmaxf(s1[i], 0.f); }
        f16x8 bS[4];
        cvt_tile(s0, hf, bS[0], bS[1]);
        cvt_tile(s1, hf, bS[2], bS[3]);

        // ---- GRU: 2 halves (j 0..31, 32..63); h update in registers ----
        f16x8 nb0, nb1, nb2, nb3;
        #pragma unroll
        for (int hnum = 0; hnum < 2; ++hnum) {
            const int tR = hnum, tZ = 2 + hnum, tN = 4 + hnum;
            f32x16 aR = z16, aZ = z16, aNi = z16, aNh = z16;
            #pragma unroll
            for (int kt = 0; kt < 4; ++kt) {
                aR  = mm(aR,  (0 * 6 + tR) * 5 + kt, bS[kt]);
                aR  = mm(aR,  (1 * 6 + tR) * 5 + kt, bH[kt]);
                aZ  = mm(aZ,  (0 * 6 + tZ) * 5 + kt, bS[kt]);
                aZ  = mm(aZ,  (1 * 6 + tZ) * 5 + kt, bH[kt]);
                aNi = mm(aNi, (0 * 6 + tN) * 5 + kt, bS[kt]);
                aNh = mm(aNh, (1 * 6 + tN) * 5 + kt, bH[kt]);
            }
            aR  = mm(aR,  (0 * 6 + tR) * 5 + 4, bC);   // bias: bih+bhh (r)
            aZ  = mm(aZ,  (0 * 6 + tZ) * 5 + 4, bC);   // bias: bih+bhh (z)
            aNi = mm(aNi, (0 * 6 + tN) * 5 + 4, bC);   // bias: bih (n)
            aNh = mm(aNh, (1 * 6 + tN) * 5 + 4, bC);   // bias: bhh (n)
            f32x16& hv = hnum ? hC1 : hC0;
            #pragma unroll
            for (int i = 0; i < 16; ++i) {
                const float r = sigm(aR[i]);
                const float z = sigm(aZ[i]);
                const float n = tanhp(aNi[i] + r * aNh[i]);
                hv[i] = n + z * (hv[i] - n);
            }
            if (hnum == 0) cvt_tile(hC0, hf, nb0, nb1);
            else           cvt_tile(hC1, hf, nb2, nb3);
        }
        bH[0] = nb0; bH[1] = nb1; bH[2] = nb2; bH[3] = nb3;

        // ---- future: decoder (d2^T rows 0..3 = output features) ----
        if (t >= 50) {
            const int fs = t - 50;
            f32x16 d1 = z16;
            #pragma unroll
            for (int kt = 0; kt < 4; ++kt) d1 = mm(d1, 60 + kt, bH[kt]);
            d1 = mm(d1, 64, bC);
            #pragma unroll
            for (int i = 0; i < 16; ++i) d1[i] = fmaxf(d1[i], 0.f);
            f16x8 bD0, bD1;
            cvt_tile(d1, hf, bD0, bD1);
            f32x16 d2 = z16;
            d2 = mm(d2, 65, bD0);
            d2 = mm(d2, 66, bD1);
            d2 = mm(d2, 67, bC);
            if (hf == 0 && l31 < 23) {
                f32x4n o;
                o[0] = d2[0]; o[1] = d2[1]; o[2] = d2[2]; o[3] = d2[3];
                *(f32x4n*)(outb + fs * 92 + l31 * 4) = o;
                *(f32x4n*)(xL + l31 * 4) = o;     // feeds next step's X^
            }
        }
    }
}

extern "C" void kernel_launch(void* const* d_in, const int* in_sizes, int n_in,
                              void* d_out, int out_size, void* d_ws, size_t ws_size,
                              hipStream_t stream) {
    (void)in_sizes; (void)n_in; (void)d_ws; (void)ws_size; (void)out_size;
    hipFuncSetAttribute((const void*)gwm_kernel,
                        hipFuncAttributeMaxDynamicSharedMemorySize, SMEM_BYTES);
    gwm_kernel<<<dim3(256), dim3(512), SMEM_BYTES, stream>>>(
        (const float*)d_in[0], (const float*)d_in[1], (const float*)d_in[2],
        (const float*)d_in[3], (const float*)d_in[4], (const float*)d_in[5],
        (const float*)d_in[6], (const float*)d_in[7], (const float*)d_in[8],
        (const float*)d_in[9], (const float*)d_in[10], (const float*)d_in[11],
        (float*)d_out);
}